// Round 1
// 7127.536 us; speedup vs baseline: 1.5984x; 1.5984x over previous
//
#include <hip/hip_runtime.h>
#include <cstdio>
#include <cstdint>
#include <math.h>

typedef float vf4 __attribute__((ext_vector_type(4)));

// ---------------- problem constants ----------------
constexpr int SEQ = 256, BATCH = 64, HID = 1024, TH3 = 3072, PLEN = 256;
constexpr float NEGV = -1000000000.0f;

constexpr int GI_CHUNK = 8;    // rec steps per fused launch (gi double-buffered)
constexpr int Q_CHUNK  = 32;   // steps per q/attention chunk

// ---------------- workspace layout (floats) ----------------
constexpr size_t OFF_H  = 1024;                   // barrier region = 4 KB
constexpr size_t OFF_GI = OFF_H + 2 * 1024 * 64;  // h_T double buffer [2][1024][64]
constexpr size_t GI_FLOATS = (size_t)GI_CHUNK * TH3 * BATCH;          // 1,572,864
constexpr size_t WS_NEED = (OFF_GI + 2 * GI_FLOATS) * sizeof(float);  // ~13.1 MB (same as prev)

// ---------------- grid barrier over rec blocks (bid 0..255) ----------------
// h-state is written WRITE-THROUGH (sc0 sc1) by relaxed-agent atomic stores, and
// __syncthreads drains vmcnt, so arrivals can be fully RELAXED (no per-WG wbl2/inv).
// Only the last arriver pays one RELEASE (orders the counter resets); every WG keeps
// exactly ONE acquire-inv per step so the L2-cached hT broadcast from 2 steps ago is
// invalidated (preserves per-XCD L2 reuse of the h broadcast).
__device__ __forceinline__ void gbar(unsigned* bar) {
  __syncthreads();  // drains each thread's vmcnt: WT h stores are at the LLC after this
  if (threadIdx.x == 0) {
    const unsigned e = __hip_atomic_load(&bar[544], __ATOMIC_RELAXED, __HIP_MEMORY_SCOPE_AGENT);
    const int g = blockIdx.x & 31;
    const unsigned o = __hip_atomic_fetch_add(&bar[g * 16], 1u, __ATOMIC_RELAXED, __HIP_MEMORY_SCOPE_AGENT);
    bool last = false;
    if (o == 7u) {
      const unsigned r = __hip_atomic_fetch_add(&bar[512], 1u, __ATOMIC_RELAXED, __HIP_MEMORY_SCOPE_AGENT);
      if (r == 31u) {
#pragma unroll
        for (int i = 0; i < 32; ++i)
          __hip_atomic_store(&bar[i * 16], 0u, __ATOMIC_RELAXED, __HIP_MEMORY_SCOPE_AGENT);
        __hip_atomic_store(&bar[512], 0u, __ATOMIC_RELAXED, __HIP_MEMORY_SCOPE_AGENT);
        __hip_atomic_fetch_add(&bar[544], 1u, __ATOMIC_RELEASE, __HIP_MEMORY_SCOPE_AGENT);
        last = true;
      }
    }
    if (!last) {
      while (__hip_atomic_load(&bar[544], __ATOMIC_RELAXED, __HIP_MEMORY_SCOPE_AGENT) == e)
        __builtin_amdgcn_s_sleep(8);
    }
    (void)__hip_atomic_load(&bar[544], __ATOMIC_ACQUIRE, __HIP_MEMORY_SCOPE_AGENT);  // one buffer_inv
  }
  __syncthreads();
}

// ---------------- fused kernel ----------------
// block layout (in blockIdx order, so rec blocks are dispatched & resident first):
//   [0,256)   rec   : GRU steps [rec_s0, rec_s0+8), grid barrier among these only
//   [.., +192) gi   : gi for chunk gi_c (24 row-tiles x 8 steps) -> gi_buf[gi_c&1]
//   [.., +512) q    : query for q-chunk q_qc -> out_hs[s][b][1024..2048) (ctx slot)
//   [.., +256) attn : scores/softmax/context for chunk at_qc (reads q from ctx slot,
//                     overwrites it with context)
__global__ __launch_bounds__(256, 2)
void k_fused(const float* __restrict__ incoming, const float* __restrict__ post,
             const float* __restrict__ h_init, const float* __restrict__ W_ih,
             const float* __restrict__ W_hh, const float* __restrict__ b_ih,
             const float* __restrict__ b_hh, const float* __restrict__ Wq,
             const float* __restrict__ bq, const int* __restrict__ length,
             const int* __restrict__ post_length, float* __restrict__ out,
             float* __restrict__ ws, int rec_s0, int last_chunk,
             int gi_c, int q_qc, int at_qc)
{
  __shared__ float lds[16384];  // 64 KB uniform -> 2 blocks/CU
  int bid = blockIdx.x;
  const int tid = threadIdx.x;

  // ================= rec path =================
  if (rec_s0 >= 0) {
    if (bid < 256) {
      float* Wl = lds;           // [12][1024]
      float* hs = lds + 12288;   // [4096]
      unsigned* bar = (unsigned*)ws;
      const int wg = bid;
      const int wave = tid >> 6, lane = tid & 63;
      float* out_hs = out + (size_t)BATCH * HID;
      const float* gip = ws + OFF_GI + (size_t)((rec_s0 >> 3) & 1) * GI_FLOATS;

      // load the WG's 12 W_hh rows into LDS once
      for (int t = tid; t < 3072; t += 256) {
        const int r = t >> 8, kq = t & 255;
        const int grow = (r >> 2) * 1024 + wg * 4 + (r & 3);
        *(vf4*)&Wl[r * 1024 + kq * 4] = *(const vf4*)&W_hh[(size_t)grow * HID + kq * 4];
      }
      const int lb = length[lane];
      const float bh0 = b_hh[0 * 1024 + wg * 4 + wave];
      const float bh1 = b_hh[1 * 1024 + wg * 4 + wave];
      const float bh2 = b_hh[2 * 1024 + wg * 4 + wave];
      const int j = wg * 4 + wave;
      if (rec_s0 == 0) {  // init transposed h state (write-through so gbar publishes it)
        __hip_atomic_store(&(ws + OFF_H)[j * 64 + lane], h_init[j],
                           __ATOMIC_RELAXED, __HIP_MEMORY_SCOPE_AGENT);
        gbar(bar);
      } else {
        __syncthreads();  // Wl ready; hT of prev launch is coherent via kernel boundary
      }

      for (int s = rec_s0; s < rec_s0 + GI_CHUNK; ++s) {
        const float* hT = ws + OFF_H + (size_t)(s & 1) * 65536;
        float* hTn = ws + OFF_H + (size_t)((s + 1) & 1) * 65536;
        // early loads: gi gates + own h (latency hidden under the GEMM)
        const size_t gib = (size_t)(s - rec_s0) * (TH3 * 64);
        const float gi_r = gip[gib + (size_t)(0 * 1024 + j) * 64 + lane];
        const float gi_z = gip[gib + (size_t)(1 * 1024 + j) * 64 + lane];
        const float gi_n = gip[gib + (size_t)(2 * 1024 + j) * 64 + lane];
        const float hold = hT[(size_t)j * 64 + lane];
        float acc[12];
#pragma unroll
        for (int r = 0; r < 12; ++r) acc[r] = 0.f;

        vf4 rbuf[4];
        {
          const vf4* src = (const vf4*)hT;
#pragma unroll
          for (int j4 = 0; j4 < 4; ++j4) rbuf[j4] = src[tid + 256 * j4];
        }
        for (int kt = 0; kt < 16; ++kt) {
          vf4* dst = (vf4*)hs;
#pragma unroll
          for (int j4 = 0; j4 < 4; ++j4) dst[tid + 256 * j4] = rbuf[j4];
          __syncthreads();
          if (kt < 15) {  // prefetch next tile during compute
            const vf4* src = (const vf4*)(hT + (kt + 1) * 4096);
#pragma unroll
            for (int j4 = 0; j4 < 4; ++j4) rbuf[j4] = src[tid + 256 * j4];
          }
#pragma unroll
          for (int kq = 0; kq < 4; ++kq) {
            const int kk = wave * 16 + kq * 4;
            vf4 wv[12];
#pragma unroll
            for (int r = 0; r < 12; ++r)
              wv[r] = *(const vf4*)&Wl[r * 1024 + kt * 64 + kk];
            float hv[4];
#pragma unroll
            for (int i = 0; i < 4; ++i) hv[i] = hs[(kk + i) * 64 + lane];
#pragma unroll
            for (int i = 0; i < 4; ++i) {
              const float hvi = hv[i];
#pragma unroll
              for (int r = 0; r < 12; ++r) acc[r] = fmaf(hvi, wv[r][i], acc[r]);
            }
          }
          __syncthreads();
        }
        // cross-wave k-reduction
#pragma unroll
        for (int r = 0; r < 12; ++r) hs[wave * 768 + r * 64 + lane] = acc[r];
        __syncthreads();
        float gsum[3];
#pragma unroll
        for (int g = 0; g < 3; ++g) {
          const int r = g * 4 + wave;
          gsum[g] = hs[r * 64 + lane] + hs[768 + r * 64 + lane] +
                    hs[1536 + r * 64 + lane] + hs[2304 + r * 64 + lane];
        }
        const float rg = 1.f / (1.f + expf(-(gi_r + gsum[0] + bh0)));
        const float zg = 1.f / (1.f + expf(-(gi_z + gsum[1] + bh1)));
        const float ng = tanhf(gi_n + rg * (gsum[2] + bh2));
        const float keep = (s < lb) ? 1.f : 0.f;
        const float hn = (ng + zg * (hold - ng)) * keep;
        // write-through transposed state (visible at LLC once vmcnt drains at gbar)
        __hip_atomic_store(&hTn[(size_t)j * 64 + lane], hn,
                           __ATOMIC_RELAXED, __HIP_MEMORY_SCOPE_AGENT);
        hs[3328 + lane * 4 + wave] = hn;  // for f4-coalesced out_hs write
        __syncthreads();
        if (tid < 64)
          *(vf4*)&out_hs[(size_t)s * (BATCH * 2048) + (size_t)tid * 2048 + wg * 4] =
              *(vf4*)&hs[3328 + tid * 4];
        if (last_chunk && s == rec_s0 + GI_CHUNK - 1) {
          out[(size_t)lane * HID + j] = hn;      // h_last straight from register
        } else if (s < rec_s0 + GI_CHUNK - 1) {
          gbar(bar);                             // last step per launch: kernel boundary syncs
        }
      }
      return;
    }
    bid -= 256;
  }

  // ================= gi path: gi[sl][row][b] = X[s]@W_ih^T + b_ih =================
  if (gi_c >= 0) {
    if (bid < 192) {
      float* Wt = lds;          // [32][128]
      float* Xs = lds + 4096;   // [32][64]
      const int rt = bid % 24, sl = bid / 24;
      const int s = gi_c * GI_CHUNK + sl;
      const int mq = tid & 31, bq_ = tid >> 5;
      const int m0 = rt * 128;
      const float* Xg = incoming + (size_t)s * (BATCH * HID);
      float* gid = ws + OFF_GI + (size_t)(gi_c & 1) * GI_FLOATS;
      float acc[4][8];
#pragma unroll
      for (int jj = 0; jj < 4; ++jj)
#pragma unroll
        for (int i = 0; i < 8; ++i) acc[jj][i] = 0.f;

      for (int kt = 0; kt < 32; ++kt) {
        const int k0 = kt * 32;
        {  // stage W tile: 128 rows x 32 k
          const int row = tid >> 1, half = tid & 1;
          const float* srcp = W_ih + (size_t)(m0 + row) * HID + k0 + half * 16;
#pragma unroll
          for (int f = 0; f < 4; ++f) {
            vf4 v = *(const vf4*)(srcp + f * 4);
            const int kb = half * 16 + f * 4;
            Wt[(kb + 0) * 128 + row] = v[0];
            Wt[(kb + 1) * 128 + row] = v[1];
            Wt[(kb + 2) * 128 + row] = v[2];
            Wt[(kb + 3) * 128 + row] = v[3];
          }
        }
        {  // stage X tile: 64 b x 32 k
          const int bb = tid >> 2, kq = tid & 3;
          const float* srcp = Xg + (size_t)bb * HID + k0;
#pragma unroll
          for (int hh = 0; hh < 2; ++hh) {
            const int slot = kq + hh * 4;
            vf4 v = *(const vf4*)(srcp + slot * 4);
            Xs[(slot * 4 + 0) * 64 + bb] = v[0];
            Xs[(slot * 4 + 1) * 64 + bb] = v[1];
            Xs[(slot * 4 + 2) * 64 + bb] = v[2];
            Xs[(slot * 4 + 3) * 64 + bb] = v[3];
          }
        }
        __syncthreads();
#pragma unroll 4
        for (int kk = 0; kk < 32; ++kk) {
          vf4 x0 = *(const vf4*)&Xs[kk * 64 + bq_ * 8];
          vf4 x1 = *(const vf4*)&Xs[kk * 64 + bq_ * 8 + 4];
          float wv[4];
#pragma unroll
          for (int jj = 0; jj < 4; ++jj) wv[jj] = Wt[kk * 128 + mq + 32 * jj];
#pragma unroll
          for (int jj = 0; jj < 4; ++jj) {
            acc[jj][0] = fmaf(wv[jj], x0[0], acc[jj][0]);
            acc[jj][1] = fmaf(wv[jj], x0[1], acc[jj][1]);
            acc[jj][2] = fmaf(wv[jj], x0[2], acc[jj][2]);
            acc[jj][3] = fmaf(wv[jj], x0[3], acc[jj][3]);
            acc[jj][4] = fmaf(wv[jj], x1[0], acc[jj][4]);
            acc[jj][5] = fmaf(wv[jj], x1[1], acc[jj][5]);
            acc[jj][6] = fmaf(wv[jj], x1[2], acc[jj][6]);
            acc[jj][7] = fmaf(wv[jj], x1[3], acc[jj][7]);
          }
        }
        __syncthreads();
      }
#pragma unroll
      for (int jj = 0; jj < 4; ++jj) {
        const int m = m0 + mq + 32 * jj;
        const float bm = b_ih[m];
        float* dst = gid + (size_t)sl * (TH3 * 64) + (size_t)m * 64 + bq_ * 8;
        vf4 o0 = {acc[jj][0] + bm, acc[jj][1] + bm, acc[jj][2] + bm, acc[jj][3] + bm};
        vf4 o1 = {acc[jj][4] + bm, acc[jj][5] + bm, acc[jj][6] + bm, acc[jj][7] + bm};
        *(vf4*)dst = o0;
        *(vf4*)(dst + 4) = o1;
      }
      return;
    }
    bid -= 192;
  }

  // ================= q path: q -> out_hs[s][b][1024..2048) =================
  if (q_qc >= 0) {
    if (bid < 512) {
      float* Wt = lds;          // [32][128]
      float* Ht = lds + 4096;   // [32][32]
      const int pt = bid & 7, b = bid >> 3;
      const int s0q = q_qc * Q_CHUNK;
      const float* Hbase = out + (size_t)BATCH * HID;
      float* outq = out + (size_t)BATCH * HID;
      const int pq = tid & 31, sq = tid >> 5;
      const int p0 = pt * 128;
      float acc[4][4];
#pragma unroll
      for (int i = 0; i < 4; ++i)
#pragma unroll
        for (int jj = 0; jj < 4; ++jj) acc[i][jj] = 0.f;

      for (int kt = 0; kt < 32; ++kt) {
        const int k0 = kt * 32;
        {  // stage Wq tile
          const int row = tid >> 1, half = tid & 1;
          const float* srcp = Wq + (size_t)(p0 + row) * HID + k0 + half * 16;
#pragma unroll
          for (int f = 0; f < 4; ++f) {
            vf4 v = *(const vf4*)(srcp + f * 4);
            const int kb = half * 16 + f * 4;
            Wt[(kb + 0) * 128 + row] = v[0];
            Wt[(kb + 1) * 128 + row] = v[1];
            Wt[(kb + 2) * 128 + row] = v[2];
            Wt[(kb + 3) * 128 + row] = v[3];
          }
        }
        {  // stage H tile: 32 sl x 32 k
          const int sl = tid >> 3, slot = tid & 7;
          vf4 v = *(const vf4*)&Hbase[(size_t)(s0q + sl) * (BATCH * 2048) + (size_t)b * 2048 + k0 + slot * 4];
          Ht[(slot * 4 + 0) * 32 + sl] = v[0];
          Ht[(slot * 4 + 1) * 32 + sl] = v[1];
          Ht[(slot * 4 + 2) * 32 + sl] = v[2];
          Ht[(slot * 4 + 3) * 32 + sl] = v[3];
        }
        __syncthreads();
#pragma unroll 4
        for (int kk = 0; kk < 32; ++kk) {
          vf4 hv = *(const vf4*)&Ht[kk * 32 + sq * 4];
          vf4 wv = *(const vf4*)&Wt[kk * 128 + pq * 4];
#pragma unroll
          for (int si = 0; si < 4; ++si)
#pragma unroll
            for (int pi = 0; pi < 4; ++pi) acc[si][pi] = fmaf(hv[si], wv[pi], acc[si][pi]);
        }
        __syncthreads();
      }
      vf4 bqv = *(const vf4*)&bq[p0 + pq * 4];
#pragma unroll
      for (int si = 0; si < 4; ++si) {
        vf4 o = {acc[si][0] + bqv[0], acc[si][1] + bqv[1], acc[si][2] + bqv[2], acc[si][3] + bqv[3]};
        *(vf4*)&outq[(size_t)(s0q + sq * 4 + si) * (BATCH * 2048) + (size_t)b * 2048 + 1024 + p0 + pq * 4] = o;
      }
      return;
    }
    bid -= 512;
  }

  // ================= attn path =================
  if (at_qc >= 0 && bid < 256) {
    float* q8   = lds;           // 8192
    float* Pt   = lds + 8192;    // 32*132 = 4224 (pad 132 for conflict-free b128)
    float* sc   = lds + 12416;   // 2048
    float* stat = lds + 14464;   // 8
    const int b = bid & 63, st = bid >> 6;
    const int wave = tid >> 6, lane = tid & 63;
    const int plen = post_length[b];
    const int sbase = at_qc * Q_CHUNK + st * 8;
    float* out_hs = out + (size_t)BATCH * HID;
    float* out_attn = out_hs + (size_t)SEQ * BATCH * 2048;

    {  // load 8 query rows from the ctx slots (written by q blocks last launch)
#pragma unroll
      for (int i = 0; i < 8; ++i) {
        const float* srcr = out_hs + (size_t)(sbase + i) * (BATCH * 2048) + (size_t)b * 2048 + 1024;
        *(vf4*)&q8[i * 1024 + tid * 4] = *(const vf4*)&srcr[tid * 4];
      }
    }
    __syncthreads();

    // scores: thread = (l = l0 + tid&31, s = tid>>5)
    const int l32 = tid & 31, sq = tid >> 5;
    for (int lt = 0; lt < 8; ++lt) {
      const int l0 = lt * 32;
      if (l0 < plen) {  // WG-uniform branch
        float a = 0.f;
        for (int ptile = 0; ptile < 8; ++ptile) {
#pragma unroll
          for (int i = 0; i < 4; ++i) {
            const int f4i = tid + 256 * i;
            const int row = f4i >> 5, c4 = f4i & 31;
            *(vf4*)&Pt[row * 132 + c4 * 4] =
                *(const vf4*)&post[(size_t)(l0 + row) * (BATCH * HID) + (size_t)b * HID + ptile * 128 + c4 * 4];
          }
          __syncthreads();
#pragma unroll 8
          for (int p4 = 0; p4 < 32; ++p4) {
            vf4 qv = *(const vf4*)&q8[sq * 1024 + ptile * 128 + p4 * 4];
            vf4 pv = *(const vf4*)&Pt[l32 * 132 + p4 * 4];
            a = fmaf(qv[0], pv[0], a);
            a = fmaf(qv[1], pv[1], a);
            a = fmaf(qv[2], pv[2], a);
            a = fmaf(qv[3], pv[3], a);
          }
          __syncthreads();
        }
        sc[sq * 256 + l0 + l32] = (l0 + l32 < plen) ? a : NEGV;
      } else {
        sc[sq * 256 + l0 + l32] = NEGV;
      }
    }
    __syncthreads();

    // softmax per s over l (wave handles s = wave, wave+4)
    for (int si = wave; si < 8; si += 4) {
      float v0 = sc[si * 256 + lane], v1 = sc[si * 256 + 64 + lane];
      float v2 = sc[si * 256 + 128 + lane], v3 = sc[si * 256 + 192 + lane];
      float m = fmaxf(fmaxf(v0, v1), fmaxf(v2, v3));
#pragma unroll
      for (int off = 32; off > 0; off >>= 1) m = fmaxf(m, __shfl_xor(m, off));
      float e0 = expf(v0 - m), e1 = expf(v1 - m), e2 = expf(v2 - m), e3 = expf(v3 - m);
      float ssum = e0 + e1 + e2 + e3;
#pragma unroll
      for (int off = 32; off > 0; off >>= 1) ssum += __shfl_xor(ssum, off);
      sc[si * 256 + lane] = e0;
      sc[si * 256 + 64 + lane] = e1;
      sc[si * 256 + 128 + lane] = e2;
      sc[si * 256 + 192 + lane] = e3;
      if (lane == 0) stat[si] = 1.f / ssum;
    }
    __syncthreads();

    // attn weights out: [s][l][b]
#pragma unroll
    for (int i = 0; i < 8; ++i) {
      const int idx = tid + 256 * i;
      const int si = idx >> 8, l = idx & 255;
      out_attn[(size_t)(sbase + si) * (PLEN * BATCH) + (size_t)l * BATCH + b] = sc[si * 256 + l] * stat[si];
    }

    // context: thread owns p4 = tid*4, all 8 s (overwrites the q slot)
    vf4 a[8];
#pragma unroll
    for (int s8 = 0; s8 < 8; ++s8) a[s8] = (vf4){0.f, 0.f, 0.f, 0.f};
    const int lr = (plen + 3) & ~3;
    for (int l = 0; l < lr; l += 4) {
      vf4 w[8];
#pragma unroll
      for (int s8 = 0; s8 < 8; ++s8) w[s8] = *(const vf4*)&sc[s8 * 256 + l];
#pragma unroll
      for (int u = 0; u < 4; ++u) {
        vf4 pv = *(const vf4*)&post[(size_t)(l + u) * (BATCH * HID) + (size_t)b * HID + tid * 4];
#pragma unroll
        for (int s8 = 0; s8 < 8; ++s8) a[s8] = a[s8] + pv * w[s8][u];
      }
    }
#pragma unroll
    for (int s8 = 0; s8 < 8; ++s8) {
      vf4 r = a[s8] * stat[s8];
      *(vf4*)&out_hs[(size_t)(sbase + s8) * (BATCH * 2048) + (size_t)b * 2048 + 1024 + tid * 4] = r;
    }
  }
}

// ---------------- host ----------------
extern "C" void kernel_launch(void* const* d_in, const int* in_sizes, int n_in,
                              void* d_out, int out_size, void* d_ws, size_t ws_size,
                              hipStream_t stream) {
  const float* incoming    = (const float*)d_in[0];
  const float* post        = (const float*)d_in[1];
  const float* h_init      = (const float*)d_in[2];
  const float* W_ih        = (const float*)d_in[3];
  const float* W_hh        = (const float*)d_in[4];
  const float* b_ih        = (const float*)d_in[5];
  const float* b_hh        = (const float*)d_in[6];
  const float* Wq          = (const float*)d_in[7];
  const float* bq          = (const float*)d_in[8];
  const int*   length      = (const int*)d_in[9];
  const int*   post_length = (const int*)d_in[10];
  float* out = (float*)d_out;
  float* ws  = (float*)d_ws;

  if (ws_size < WS_NEED) {
    fprintf(stderr, "[gru_attn] ERROR: ws too small (%zu < %zu)\n", ws_size, WS_NEED);
    return;
  }
  hipMemsetAsync(d_ws, 0, 4096, stream);  // barrier counters

  // priming launch: gi for chunk 0 (parity 0)
  hipLaunchKernelGGL(k_fused, dim3(192), dim3(256), 0, stream,
                     incoming, post, h_init, W_ih, W_hh, b_ih, b_hh, Wq, bq,
                     length, post_length, out, ws,
                     /*rec_s0*/-1, /*last*/0, /*gi_c*/0, /*q_qc*/-1, /*at_qc*/-1);

  // fused schedule: rec chunk c || gi chunk c+1 || q/attn for completed steps
  //   q-chunk qc at launch 4qc+4 (reads steps [32qc,32qc+32), done by launch 4qc+3)
  //   attn qc at launch 4qc+5 (reads q written previous launch)
  for (int c = 0; c <= 33; ++c) {
    const int rec_s0 = (c < 32) ? c * GI_CHUNK : -1;
    const int last   = (c == 31) ? 1 : 0;
    const int gi_c   = (c >= 0 && c < 31) ? c + 1 : -1;
    int q_qc = -1, at_qc = -1;
    if (c >= 4 && c <= 28 && (c & 3) == 0) q_qc = c / 4 - 1;
    if (c == 32) q_qc = 7;
    if (c >= 5 && c <= 29 && (c & 3) == 1) at_qc = (c - 5) / 4;
    if (c == 33) at_qc = 7;
    const int nb = (rec_s0 >= 0 ? 256 : 0) + (gi_c >= 0 ? 192 : 0) +
                   (q_qc >= 0 ? 512 : 0) + (at_qc >= 0 ? 256 : 0);
    if (nb == 0) continue;
    hipLaunchKernelGGL(k_fused, dim3(nb), dim3(256), 0, stream,
                       incoming, post, h_init, W_ih, W_hh, b_ih, b_hh, Wq, bq,
                       length, post_length, out, ws,
                       rec_s0, last, gi_c, q_qc, at_qc);
  }
}